// Round 1
// baseline (172.203 us; speedup 1.0000x reference)
//
#include <hip/hip_runtime.h>
#include <stdint.h>

// Problem constants (B, N, H, L) = (4096, 512, 1024, 8)
static constexpr int B_DIM = 4096;
static constexpr int N_DIM = 512;
static constexpr int H_DIM = 1024;
static constexpr int L_DIM = 8;
static constexpr int HL    = H_DIM * L_DIM;   // 8192
static constexpr int KC    = 2 * N_DIM;       // 1024 combined K for [x | x^2]

typedef __attribute__((ext_vector_type(8))) short short8;  // 8 bf16 = 4 VGPRs
typedef __attribute__((ext_vector_type(4))) float f32x4;

#define BM 128
#define BN 128
#define BK 32

// round-to-nearest-even fp32 -> bf16 (bit pattern), no hip_bf16.h dependency
__device__ __forceinline__ uint16_t f2bf(float f) {
  uint32_t u = __float_as_uint(f);
  u += 0x7fffu + ((u >> 16) & 1u);
  return (uint16_t)(u >> 16);
}

__device__ __forceinline__ void stage16(const uint16_t* g, uint16_t* l) {
  __builtin_amdgcn_global_load_lds(
      (const __attribute__((address_space(1))) void*)g,
      (__attribute__((address_space(3))) void*)l, 16, 0, 0);
}

// ---------- prep kernels ----------
// xcomb[b, 0:512] = bf16(x[b,:]) ; xcomb[b, 512:1024] = bf16(x[b,:]^2)
__global__ void prep_x_kernel(const float* __restrict__ x, uint16_t* __restrict__ xcomb) {
  int idx = blockIdx.x * blockDim.x + threadIdx.x;   // B*N threads
  int b = idx >> 9, n = idx & 511;
  float v = x[idx];
  xcomb[(size_t)b * KC + n]         = f2bf(v);
  xcomb[(size_t)b * KC + N_DIM + n] = f2bf(v * v);
}

// betab = bf16(beta), already (HL, N) row-major = B^T layout
__global__ void prep_beta_kernel(const float* __restrict__ beta, uint16_t* __restrict__ bb) {
  int idx = blockIdx.x * blockDim.x + threadIdx.x;   // HL*N threads
  bb[idx] = f2bf(beta[idx]);
}

// combW[h, 0:512] = bf16(W[h,:]) ; combW[h, 512:1024] = bf16(-0.5 * sum_l beta[h,l,:]^2)
__global__ void prep_w_kernel(const float* __restrict__ W, const float* __restrict__ beta,
                              uint16_t* __restrict__ combW) {
  int idx = blockIdx.x * blockDim.x + threadIdx.x;   // H*N threads
  int h = idx >> 9, n = idx & 511;
  combW[(size_t)h * KC + n] = f2bf(W[idx]);
  float s = 0.f;
#pragma unroll
  for (int l = 0; l < L_DIM; ++l) {
    float v = beta[((size_t)h * L_DIM + l) * N_DIM + n];
    s += v * v;
  }
  combW[(size_t)h * KC + N_DIM + n] = f2bf(-0.5f * s);
}

// ---------- GEMM (m97 structure) ----------
// C[b, col] = sum_k A[b,k] * Bt[col,k]
// FM=true : KTOT=512, LDB=512, epilogue out[b,h] = 0.5*sum over 8-col groups of C^2
// FM=false: KTOT=1024, LDB=1024, epilogue out[b,col] += C + bias[col]
template <int KTOT, bool FM>
__global__ __launch_bounds__(256) void gemm_kernel(
    const uint16_t* __restrict__ A,    // lda = KC
    const uint16_t* __restrict__ Bt,   // ldb = LDB
    const float* __restrict__ bias,
    float* __restrict__ out)           // (B_DIM, H_DIM)
{
  constexpr int LDA = KC;
  constexpr int LDB = FM ? N_DIM : KC;

  __shared__ __align__(16) uint16_t As[BM * BK];  // 8 KB, row-major [m][k]
  __shared__ __align__(16) uint16_t Bs[BN * BK];  // 8 KB, row-major [col][k]

  const int tid  = threadIdx.x;
  const int lane = tid & 63;
  const int wave = tid >> 6;
  const int wm = wave >> 1, wn = wave & 1;   // 2x2 waves, each 64x64

  const int row0 = blockIdx.y * BM;
  const int col0 = blockIdx.x * BN;

  f32x4 acc[4][4] = {};

  // staging: 512 chunks of 16B per tile; thread handles chunks tid and tid+256
  const int m0 = tid >> 2, kq0 = (tid & 3) * 8;
  const int m1 = (tid + 256) >> 2;  // kq same (tid+256 ≡ tid mod 4)

  for (int kt = 0; kt < KTOT; kt += BK) {
    stage16(A + (size_t)(row0 + m0) * LDA + kt + kq0, As + tid * 8);
    stage16(A + (size_t)(row0 + m1) * LDA + kt + kq0, As + (tid + 256) * 8);
    stage16(Bt + (size_t)(col0 + m0) * LDB + kt + kq0, Bs + tid * 8);
    stage16(Bt + (size_t)(col0 + m1) * LDB + kt + kq0, Bs + (tid + 256) * 8);
    __syncthreads();  // drains vmcnt(0) before barrier

    const int fr = lane & 15;          // fragment row (m or col)
    const int ko = (lane >> 4) * 8;    // k offset within BK
    short8 af[4], bfr[4];
#pragma unroll
    for (int i = 0; i < 4; ++i)
      af[i] = *(const short8*)(As + (wm * 64 + i * 16 + fr) * BK + ko);
#pragma unroll
    for (int j = 0; j < 4; ++j)
      bfr[j] = *(const short8*)(Bs + (wn * 64 + j * 16 + fr) * BK + ko);
#pragma unroll
    for (int i = 0; i < 4; ++i)
#pragma unroll
      for (int j = 0; j < 4; ++j)
        acc[i][j] = __builtin_amdgcn_mfma_f32_16x16x32_bf16(af[i], bfr[j], acc[i][j], 0, 0, 0);
    __syncthreads();
  }

  // epilogue. C/D layout: col = lane&15, row = (lane>>4)*4 + reg
  const int cfr  = lane & 15;
  const int quad = lane >> 4;
  if (FM) {
    const int hcol0 = blockIdx.x * (BN / L_DIM);  // 16 h per block
#pragma unroll
    for (int i = 0; i < 4; ++i) {
#pragma unroll
      for (int j = 0; j < 4; ++j) {
        const int h_in = wn * 8 + j * 2 + (cfr >> 3);
        const int rowb = row0 + wm * 64 + i * 16 + quad * 4;
#pragma unroll
        for (int r = 0; r < 4; ++r) {
          float v = acc[i][j][r];
          v = v * v;
          // butterfly over lane bits 0..2: sums squares across the 8 l-columns of one h
          v += __shfl_xor(v, 1);
          v += __shfl_xor(v, 2);
          v += __shfl_xor(v, 4);
          if ((lane & 7) == 0)
            out[(size_t)(rowb + r) * H_DIM + hcol0 + h_in] = 0.5f * v;
        }
      }
    }
  } else {
#pragma unroll
    for (int i = 0; i < 4; ++i) {
#pragma unroll
      for (int j = 0; j < 4; ++j) {
        const int col  = col0 + wn * 64 + j * 16 + cfr;
        const int rowb = row0 + wm * 64 + i * 16 + quad * 4;
        const float bs = bias[col];
#pragma unroll
        for (int r = 0; r < 4; ++r) {
          size_t o = (size_t)(rowb + r) * H_DIM + col;
          out[o] += acc[i][j][r] + bs;
        }
      }
    }
  }
}

extern "C" void kernel_launch(void* const* d_in, const int* in_sizes, int n_in,
                              void* d_out, int out_size, void* d_ws, size_t ws_size,
                              hipStream_t stream) {
  const float* x    = (const float*)d_in[0];  // (4096, 512)
  const float* beta = (const float*)d_in[1];  // (1024, 8, 512)
  const float* W    = (const float*)d_in[2];  // (1024, 512)
  const float* bias = (const float*)d_in[3];  // (1024,)
  float* out = (float*)d_out;                 // (4096, 1024)

  uint16_t* xcomb = (uint16_t*)d_ws;                        // 4096*1024 bf16 = 8 MB
  uint16_t* betab = xcomb + (size_t)B_DIM * KC;             // 8192*512  bf16 = 8 MB
  uint16_t* combW = betab + (size_t)HL * N_DIM;             // 1024*1024 bf16 = 2 MB

  prep_x_kernel<<<B_DIM * N_DIM / 256, 256, 0, stream>>>(x, xcomb);
  prep_beta_kernel<<<HL * N_DIM / 256, 256, 0, stream>>>(beta, betab);
  prep_w_kernel<<<H_DIM * N_DIM / 256, 256, 0, stream>>>(W, beta, combW);

  // fm part: out = 0.5 * sum_l s^2
  gemm_kernel<N_DIM, true><<<dim3(HL / BN, B_DIM / BM), 256, 0, stream>>>(
      xcomb, betab, nullptr, out);
  // linear - 0.5*ssq + bias: out += [x|x^2] @ combW^T + b
  gemm_kernel<KC, false><<<dim3(H_DIM / BN, B_DIM / BM), 256, 0, stream>>>(
      xcomb, combW, bias, out);
}

// Round 2
// 165.622 us; speedup vs baseline: 1.0397x; 1.0397x over previous
//
#include <hip/hip_runtime.h>
#include <stdint.h>

// Problem constants (B, N, H, L) = (4096, 512, 1024, 8)
static constexpr int B_DIM = 4096;
static constexpr int N_DIM = 512;
static constexpr int H_DIM = 1024;
static constexpr int L_DIM = 8;
static constexpr int HL    = H_DIM * L_DIM;   // 8192
static constexpr int KC    = 2 * N_DIM;       // 1024 combined K for [x | x^2]

typedef __attribute__((ext_vector_type(8))) short short8;  // 8 bf16 = 4 VGPRs
typedef __attribute__((ext_vector_type(4))) float f32x4;

#define BK 32

// round-to-nearest-even fp32 -> bf16 (bit pattern)
__device__ __forceinline__ uint16_t f2bf(float f) {
  uint32_t u = __float_as_uint(f);
  u += 0x7fffu + ((u >> 16) & 1u);
  return (uint16_t)(u >> 16);
}

__device__ __forceinline__ void stage16(const uint16_t* g, uint16_t* l) {
  __builtin_amdgcn_global_load_lds(
      (const __attribute__((address_space(1))) void*)g,
      (__attribute__((address_space(3))) void*)l, 16, 0, 0);
}

// ---------- fused prep kernel ----------
// region 0: betab = bf16(beta)                        (HL*N elems)
// region 1: xcomb[b,0:512]=bf16(x), [512:1024]=bf16(x^2)  (B*N elems)
// region 2: combW[h,0:512]=bf16(W), [512:1024]=bf16(-0.5*sum_l beta^2)  (H*N)
__global__ void prep_kernel(const float* __restrict__ x, const float* __restrict__ beta,
                            const float* __restrict__ W,
                            uint16_t* __restrict__ xcomb, uint16_t* __restrict__ betab,
                            uint16_t* __restrict__ combW) {
  int idx = blockIdx.x * 256 + threadIdx.x;
  if (idx < HL * N_DIM) {                    // beta cast
    betab[idx] = f2bf(beta[idx]);
    return;
  }
  idx -= HL * N_DIM;
  if (idx < B_DIM * N_DIM) {                 // x | x^2
    int b = idx >> 9, n = idx & 511;
    float v = x[idx];
    xcomb[(size_t)b * KC + n]         = f2bf(v);
    xcomb[(size_t)b * KC + N_DIM + n] = f2bf(v * v);
    return;
  }
  idx -= B_DIM * N_DIM;                      // W | -0.5*sum_l beta^2
  int h = idx >> 9, n = idx & 511;
  combW[(size_t)h * KC + n] = f2bf(W[idx]);
  float s = 0.f;
#pragma unroll
  for (int l = 0; l < L_DIM; ++l) {
    float v = beta[((size_t)h * L_DIM + l) * N_DIM + n];
    s += v * v;
  }
  combW[(size_t)h * KC + N_DIM + n] = f2bf(-0.5f * s);
}

// ---------- GEMM (m97 structure + XOR bank swizzle) ----------
// C[b, col] = sum_k A[b,k] * Bt[col,k]
// LDS layout: row m of a tile holds 4 chunks of 8 bf16 (16B); chunk c of row m
// is stored at slot c' = c ^ ((m>>1)&3). Staging permutes the SOURCE address
// (global_load_lds dest must stay base + lane*16 contiguous); readers apply
// the same swizzle. Spreads a quad's 16 lanes over 8 banks (2-way = free)
// instead of 2 banks (8-way = 2.9x).
template <int BM_, int BN_, int KTOT, bool FM>
__global__ __launch_bounds__(256) void gemm_kernel(
    const uint16_t* __restrict__ A,    // lda = KC
    const uint16_t* __restrict__ Bt,   // ldb
    const float* __restrict__ bias,
    float* __restrict__ out)           // (B_DIM, H_DIM)
{
  constexpr int LDA = KC;
  constexpr int LDB = FM ? N_DIM : KC;
  constexpr int MI  = BM_ / 32;        // frags per wave (m)
  constexpr int NJ  = BN_ / 32;        // frags per wave (n)
  constexpr int CHA = BM_ * BK / 8;    // 16B chunks in As
  constexpr int CHB = BN_ * BK / 8;

  __shared__ __align__(16) uint16_t As[BM_ * BK];
  __shared__ __align__(16) uint16_t Bs[BN_ * BK];

  const int tid  = threadIdx.x;
  const int lane = tid & 63;
  const int wave = tid >> 6;
  const int wm = wave >> 1, wn = wave & 1;   // 2x2 waves

  const int row0 = blockIdx.y * BM_;
  const int col0 = blockIdx.x * BN_;

  f32x4 acc[MI][NJ] = {};

  const int fr   = lane & 15;
  const int quad = lane >> 4;

  for (int kt = 0; kt < KTOT; kt += BK) {
#pragma unroll
    for (int s = tid; s < CHA; s += 256) {
      int m = s >> 2, cp = s & 3, c = cp ^ ((m >> 1) & 3);
      stage16(A + (size_t)(row0 + m) * LDA + kt + c * 8, As + s * 8);
    }
#pragma unroll
    for (int s = tid; s < CHB; s += 256) {
      int m = s >> 2, cp = s & 3, c = cp ^ ((m >> 1) & 3);
      stage16(Bt + (size_t)(col0 + m) * LDB + kt + c * 8, Bs + s * 8);
    }
    __syncthreads();  // compiler drains vmcnt(0) here

    short8 af[MI], bfr[NJ];
#pragma unroll
    for (int i = 0; i < MI; ++i) {
      int m = wm * (BM_ / 2) + i * 16 + fr;
      int cp = quad ^ ((m >> 1) & 3);
      af[i] = *(const short8*)(As + (m * 4 + cp) * 8);
    }
#pragma unroll
    for (int j = 0; j < NJ; ++j) {
      int m = wn * (BN_ / 2) + j * 16 + fr;
      int cp = quad ^ ((m >> 1) & 3);
      bfr[j] = *(const short8*)(Bs + (m * 4 + cp) * 8);
    }
#pragma unroll
    for (int i = 0; i < MI; ++i)
#pragma unroll
      for (int j = 0; j < NJ; ++j)
        acc[i][j] = __builtin_amdgcn_mfma_f32_16x16x32_bf16(af[i], bfr[j], acc[i][j], 0, 0, 0);
    __syncthreads();
  }

  // epilogue. C/D layout: col = lane&15, row = (lane>>4)*4 + reg
  if (FM) {
    const int hcol0 = blockIdx.x * (BN_ / L_DIM);  // h columns per block
#pragma unroll
    for (int i = 0; i < MI; ++i) {
#pragma unroll
      for (int j = 0; j < NJ; ++j) {
        const int h_in = wn * (BN_ / 16) + j * 2 + (fr >> 3);
        const int rowb = row0 + wm * (BM_ / 2) + i * 16 + quad * 4;
#pragma unroll
        for (int r = 0; r < 4; ++r) {
          float v = acc[i][j][r];
          v = v * v;
          v += __shfl_xor(v, 1);   // butterfly over l = lane bits 0..2
          v += __shfl_xor(v, 2);
          v += __shfl_xor(v, 4);
          if ((lane & 7) == 0)
            out[(size_t)(rowb + r) * H_DIM + hcol0 + h_in] = 0.5f * v;
        }
      }
    }
  } else {
#pragma unroll
    for (int i = 0; i < MI; ++i) {
#pragma unroll
      for (int j = 0; j < NJ; ++j) {
        const int col  = col0 + wn * (BN_ / 2) + j * 16 + fr;
        const int rowb = row0 + wm * (BM_ / 2) + i * 16 + quad * 4;
        const float bs = bias[col];
#pragma unroll
        for (int r = 0; r < 4; ++r) {
          size_t o = (size_t)(rowb + r) * H_DIM + col;
          out[o] += acc[i][j][r] + bs;
        }
      }
    }
  }
}

extern "C" void kernel_launch(void* const* d_in, const int* in_sizes, int n_in,
                              void* d_out, int out_size, void* d_ws, size_t ws_size,
                              hipStream_t stream) {
  const float* x    = (const float*)d_in[0];  // (4096, 512)
  const float* beta = (const float*)d_in[1];  // (1024, 8, 512)
  const float* W    = (const float*)d_in[2];  // (1024, 512)
  const float* bias = (const float*)d_in[3];  // (1024,)
  float* out = (float*)d_out;                 // (4096, 1024)

  uint16_t* xcomb = (uint16_t*)d_ws;                        // 4096*1024 bf16 = 8 MB
  uint16_t* betab = xcomb + (size_t)B_DIM * KC;             // 8192*512  bf16 = 8 MB
  uint16_t* combW = betab + (size_t)HL * N_DIM;             // 1024*1024 bf16 = 2 MB

  // fused prep: beta cast (4.19M) + x|x^2 (2.10M) + combW (0.52M) = 6.82M threads
  const int prep_elems = HL * N_DIM + B_DIM * N_DIM + H_DIM * N_DIM;
  prep_kernel<<<(prep_elems + 255) / 256, 256, 0, stream>>>(x, beta, W, xcomb, betab, combW);

  // fm part: out = 0.5 * sum_l s^2   (grid 64 x 32 = 2048 blocks)
  gemm_kernel<128, 128, N_DIM, true><<<dim3(HL / 128, B_DIM / 128), 256, 0, stream>>>(
      xcomb, betab, nullptr, out);
  // linear - 0.5*ssq + bias: out += [x|x^2] @ combW^T + b  (grid 16 x 32 = 512 blocks)
  gemm_kernel<128, 64, KC, false><<<dim3(H_DIM / 64, B_DIM / 128), 256, 0, stream>>>(
      xcomb, combW, bias, out);
}